// Round 7
// baseline (327.680 us; speedup 1.0000x reference)
//
#include <hip/hip_runtime.h>

#define B_ 8
#define N_ 1024
#define DIM_ 512
#define H_ 8
#define DH_ 64
#define SCALE_ 0.125f
#define EPS_ 1e-6f
#define EPSN_ (1e-6f / 1024.0f)
#define C2_ (0.125f * 1.4426950408889634f)   // SCALE * log2(e)

typedef unsigned short u16;
typedef __attribute__((ext_vector_type(8))) short short8;
typedef __attribute__((ext_vector_type(8))) unsigned short ushort8;
typedef __attribute__((ext_vector_type(4))) unsigned short ushort4v;
typedef __attribute__((ext_vector_type(4))) float f32x4;

__device__ __forceinline__ u16 f2b(float f) {
    union { float f; unsigned u; } v; v.f = f;
    unsigned r = v.u + 0x7fffu + ((v.u >> 16) & 1u);
    return (u16)(r >> 16);
}

__device__ __forceinline__ f32x4 mfma16(short8 a, short8 b, f32x4 c) {
    return __builtin_amdgcn_mfma_f32_16x16x32_bf16(a, b, c, 0, 0, 0);
}

// in [R][C] f32 -> out [C][R] bf16
__global__ void cvt_transpose(const float* __restrict__ in, u16* __restrict__ out,
                              int R, int C) {
    int idx = blockIdx.x * 256 + threadIdx.x;
    if (idx >= R * C) return;
    int c = idx / R, r = idx - c * R;
    out[idx] = f2b(in[(size_t)r * C + c]);
}

// flat f32 -> bf16, 8 elems/thread
__global__ void cvt_bf16(const float* __restrict__ in, u16* __restrict__ out, int n) {
    int idx = (blockIdx.x * 256 + threadIdx.x) * 8;
    if (idx >= n) return;
    float4 f0 = *(const float4*)(in + idx);
    float4 f1 = *(const float4*)(in + idx + 4);
    ushort8 o;
    o[0]=f2b(f0.x); o[1]=f2b(f0.y); o[2]=f2b(f0.z); o[3]=f2b(f0.w);
    o[4]=f2b(f1.x); o[5]=f2b(f1.y); o[6]=f2b(f1.z); o[7]=f2b(f1.w);
    *(ushort8*)(out + idx) = o;
}

// Xb [8192][512] bf16 @ BT [1536][512] bf16 (W_qkv^T) -> scatter Q,K,Vt bf16
__global__ __launch_bounds__(256) void gemm_qkv(
    const u16* __restrict__ Xb, const u16* __restrict__ BT,
    u16* __restrict__ Qw, u16* __restrict__ Kw, u16* __restrict__ Vt) {
    __shared__ u16 al[64][72];
    __shared__ u16 bl[64][72];
    const int t = threadIdx.x;
    const int w = t >> 6, l = t & 63, lg = l >> 4, lr = l & 15;
    const int rowbase = blockIdx.y * 64, colbase = blockIdx.x * 64;
    const int r = t >> 2, cg = (t & 3) * 16;

    f32x4 acc[4];
#pragma unroll
    for (int i = 0; i < 4; i++) acc[i] = (f32x4){0.f, 0.f, 0.f, 0.f};

    for (int k0 = 0; k0 < DIM_; k0 += 64) {
        const u16* ap = Xb + (size_t)(rowbase + r) * DIM_ + k0 + cg;
        *(ushort8*)&al[r][cg] = *(const ushort8*)ap;
        *(ushort8*)&al[r][cg + 8] = *(const ushort8*)(ap + 8);
        const u16* bp = BT + (size_t)(colbase + r) * DIM_ + k0 + cg;
        *(ushort8*)&bl[r][cg] = *(const ushort8*)bp;
        *(ushort8*)&bl[r][cg + 8] = *(const ushort8*)(bp + 8);
        __syncthreads();
#pragma unroll
        for (int kk = 0; kk < 64; kk += 32) {
            short8 af = *(const short8*)&al[16 * w + lr][kk + 8 * lg];
#pragma unroll
            for (int ct = 0; ct < 4; ct++) {
                short8 bf = *(const short8*)&bl[ct * 16 + lr][kk + 8 * lg];
                acc[ct] = mfma16(af, bf, acc[ct]);
            }
        }
        __syncthreads();
    }

#pragma unroll
    for (int ct = 0; ct < 4; ct++) {
#pragma unroll
        for (int j = 0; j < 4; j++) {
            int token = rowbase + 16 * w + 4 * lg + j;
            int b = token >> 10, n = token & (N_ - 1);
            int c = colbase + ct * 16 + lr;
            u16 v = f2b(acc[ct][j]);
            if (c < 512) {
                int h = c >> 6, d = c & 63;
                Qw[((size_t)(b * H_ + h) * N_ + n) * DH_ + d] = v;
            } else if (c < 1024) {
                int c2 = c - 512, h = c2 >> 6, d = c2 & 63;
                Kw[((size_t)(b * H_ + h) * N_ + n) * DH_ + d] = v;
            } else {
                int c2 = c - 1024, h = c2 >> 6, d = c2 & 63;
                Vt[((size_t)(b * H_ + h) * DH_ + d) * N_ + n] = v;
            }
        }
    }
}

// ---- decoupled attention: sums -> writer / pv ----
// Common mapping: 2048 blocks; block = 32 q-rows x (2 col-halves), 4 waves.
// bh = g*8+xcd keeps each (b,h)'s K/V on one XCD L2.

// Kernel 1: row sums only. Writes rip=1/sp, rpo=1/(so+eps) per q-row.
__global__ __launch_bounds__(256) void attn_sums(
    const u16* __restrict__ Qw, const u16* __restrict__ Kw,
    const float* __restrict__ policy, float* __restrict__ rip_g, float* __restrict__ rpo_g) {
    __shared__ float red[4][2][16];
    __shared__ float maskL[N_];
    const int t = threadIdx.x;
    const int wid = t >> 6, l = t & 63, lg = l >> 4, lr = l & 15;
    const int rowHalf = wid >> 1, colHalf = wid & 1;
    const int bid = blockIdx.x;
    const int xcd = bid & 7, qq = bid >> 3;
    const int rt = qq & 31, g = qq >> 5;
    const int bh = g * 8 + xcd;
    const int b = bh >> 3;
    const int n0 = rt * 32 + rowHalf * 16;
    const int cb = colHalf * 512;
    const int q = n0 + lr;

    const u16* Qb = Qw + ((size_t)bh * N_ + n0) * DH_;
    const u16* Kb = Kw + (size_t)bh * N_ * DH_;
    const float* pol = policy + b * N_;
    {
        float4 pv = *(const float4*)(pol + t * 4);
        maskL[t * 4 + 0] = pv.x > 0.5f ? 1.f : 0.f;
        maskL[t * 4 + 1] = pv.y > 0.5f ? 1.f : 0.f;
        maskL[t * 4 + 2] = pv.z > 0.5f ? 1.f : 0.f;
        maskL[t * 4 + 3] = pv.w > 0.5f ? 1.f : 0.f;
    }
    __syncthreads();

    short8 qf0 = *(const short8*)(Qb + lr * DH_ + 8 * lg);
    short8 qf1 = *(const short8*)(Qb + lr * DH_ + 32 + 8 * lg);

    float sp = 0.f, so = 0.f;
#pragma unroll 2
    for (int jt = 0; jt < 32; ++jt) {
        int k0i = cb + jt * 16;
        const u16* kp = Kb + (size_t)(k0i + lr) * DH_ + 8 * lg;
        short8 kf0 = *(const short8*)kp;
        short8 kf1 = *(const short8*)(kp + 32);
        f32x4 d = {0.f, 0.f, 0.f, 0.f};
        d = mfma16(kf0, qf0, d);
        d = mfma16(kf1, qf1, d);
        int kb2 = k0i + 4 * lg;
        f32x4 m4 = *(const f32x4*)&maskL[kb2];
#pragma unroll
        for (int j = 0; j < 4; j++) {
            float E = exp2f(d[j] * C2_);
            float mm = (kb2 + j == q) ? 1.f : m4[j];
            sp += E;
            so = fmaf(E, mm, so);
        }
    }
    sp += __shfl_xor(sp, 16); sp += __shfl_xor(sp, 32);
    so += __shfl_xor(so, 16); so += __shfl_xor(so, 32);
    if (l < 16) { red[wid][0][l] = sp; red[wid][1][l] = so; }
    __syncthreads();
    if (colHalf == 0 && l < 16) {
        float spc = sp + red[wid ^ 1][0][l];
        float soc = so + red[wid ^ 1][1][l];
        rip_g[(size_t)bh * N_ + n0 + l] = 1.f / spc;
        rpo_g[(size_t)bh * N_ + n0 + l] = 1.f / (soc + EPS_);
    }
}

// Kernel 2: plain-softmax stream. E*rip = exp2(d*C2 + log2(rip)).
// No LDS, no barriers, pure recompute+store.
__global__ __launch_bounds__(256) void attn_writer(
    const u16* __restrict__ Qw, const u16* __restrict__ Kw,
    const float* __restrict__ rip_g, float* __restrict__ softout) {
    const int t = threadIdx.x;
    const int wid = t >> 6, l = t & 63, lg = l >> 4, lr = l & 15;
    const int rowHalf = wid >> 1, colHalf = wid & 1;
    const int bid = blockIdx.x;
    const int xcd = bid & 7, qq = bid >> 3;
    const int rt = qq & 31, g = qq >> 5;
    const int bh = g * 8 + xcd;
    const int n0 = rt * 32 + rowHalf * 16;
    const int cb = colHalf * 512;
    const int q = n0 + lr;

    const u16* Qb = Qw + ((size_t)bh * N_ + n0) * DH_;
    const u16* Kb = Kw + (size_t)bh * N_ * DH_;

    short8 qf0 = *(const short8*)(Qb + lr * DH_ + 8 * lg);
    short8 qf1 = *(const short8*)(Qb + lr * DH_ + 32 + 8 * lg);
    const float lrip = __log2f(rip_g[(size_t)bh * N_ + q]);
    float* srow = softout + ((size_t)bh * N_ + q) * N_ + cb;

#pragma unroll 4
    for (int jt = 0; jt < 32; ++jt) {
        const u16* kp = Kb + (size_t)(cb + jt * 16 + lr) * DH_ + 8 * lg;
        short8 kf0 = *(const short8*)kp;
        short8 kf1 = *(const short8*)(kp + 32);
        f32x4 d = {0.f, 0.f, 0.f, 0.f};
        d = mfma16(kf0, qf0, d);
        d = mfma16(kf1, qf1, d);
        f32x4 ov;
#pragma unroll
        for (int j = 0; j < 4; j++) ov[j] = exp2f(fmaf(d[j], C2_, lrip));
        *(f32x4*)(srow + jt * 16 + 4 * lg) = ov;
    }
}

// Kernel 3: policy-weighted PV. P = exp2(d*C2+log2(rpo))*mm + eps/N*rpo.
__global__ __launch_bounds__(256) void attn_pv(
    const u16* __restrict__ Qw, const u16* __restrict__ Kw, const u16* __restrict__ Vt,
    const float* __restrict__ policy, const float* __restrict__ rpo_g,
    u16* __restrict__ outpre) {
    __shared__ u16 wl[4][16][72];
    __shared__ float apvbuf[2][16][66];
    __shared__ float maskL[N_];
    const int t = threadIdx.x;
    const int wid = t >> 6, l = t & 63, lg = l >> 4, lr = l & 15;
    const int rowHalf = wid >> 1, colHalf = wid & 1;
    const int bid = blockIdx.x;
    const int xcd = bid & 7, qq = bid >> 3;
    const int rt = qq & 31, g = qq >> 5;
    const int bh = g * 8 + xcd;
    const int b = bh >> 3, h = bh & 7;
    const int n0 = rt * 32 + rowHalf * 16;
    const int cb = colHalf * 512;
    const int q = n0 + lr;

    const u16* Qb = Qw + ((size_t)bh * N_ + n0) * DH_;
    const u16* Kb = Kw + (size_t)bh * N_ * DH_;
    const u16* Vb = Vt + (size_t)bh * DH_ * N_;
    const float* pol = policy + b * N_;
    {
        float4 pv = *(const float4*)(pol + t * 4);
        maskL[t * 4 + 0] = pv.x > 0.5f ? 1.f : 0.f;
        maskL[t * 4 + 1] = pv.y > 0.5f ? 1.f : 0.f;
        maskL[t * 4 + 2] = pv.z > 0.5f ? 1.f : 0.f;
        maskL[t * 4 + 3] = pv.w > 0.5f ? 1.f : 0.f;
    }
    __syncthreads();

    short8 qf0 = *(const short8*)(Qb + lr * DH_ + 8 * lg);
    short8 qf1 = *(const short8*)(Qb + lr * DH_ + 32 + 8 * lg);
    const float rpo = rpo_g[(size_t)bh * N_ + q];
    const float lrpo = __log2f(rpo);
    const float eb = EPSN_ * rpo;

    f32x4 apv[4];
#pragma unroll
    for (int i = 0; i < 4; i++) apv[i] = (f32x4){0, 0, 0, 0};

    for (int c = 0; c < 8; ++c) {
#pragma unroll
        for (int sub = 0; sub < 4; ++sub) {
            int jt = c * 4 + sub;
            int k0i = cb + jt * 16;
            const u16* kp = Kb + (size_t)(k0i + lr) * DH_ + 8 * lg;
            short8 kf0 = *(const short8*)kp;
            short8 kf1 = *(const short8*)(kp + 32);
            f32x4 d = {0.f, 0.f, 0.f, 0.f};
            d = mfma16(kf0, qf0, d);
            d = mfma16(kf1, qf1, d);
            int kb2 = k0i + 4 * lg;
            f32x4 m4 = *(const f32x4*)&maskL[kb2];
            ushort4v wv;
#pragma unroll
            for (int j = 0; j < 4; j++) {
                float e2 = exp2f(fmaf(d[j], C2_, lrpo));
                float mm = (kb2 + j == q) ? 1.f : m4[j];
                wv[j] = f2b(fmaf(e2, mm, eb));
            }
            *(ushort4v*)&wl[wid][lr][sub * 16 + 4 * lg] = wv; // ds_write_b64
        }
        // same-wave LDS RAW: compiler inserts lgkmcnt waits
#pragma unroll
        for (int ks = 0; ks < 64; ks += 32) {
            short8 af = *(const short8*)&wl[wid][lr][ks + 8 * lg];
#pragma unroll
            for (int dt = 0; dt < 4; dt++) {
                const u16* vp = Vb + (size_t)(dt * 16 + lr) * N_ + cb + c * 64 + ks + 8 * lg;
                short8 vf = *(const short8*)vp;
                apv[dt] = mfma16(af, vf, apv[dt]);
            }
        }
    }

    if (colHalf == 1) {
#pragma unroll
        for (int dt = 0; dt < 4; dt++)
#pragma unroll
            for (int j = 0; j < 4; j++)
                apvbuf[rowHalf][4 * lg + j][dt * 16 + lr] = apv[dt][j];
    }
    __syncthreads();
    if (colHalf == 0) {
#pragma unroll
        for (int dt = 0; dt < 4; dt++) {
#pragma unroll
            for (int j = 0; j < 4; j++) {
                int row = 4 * lg + j;
                float v = apv[dt][j] + apvbuf[rowHalf][row][dt * 16 + lr];
                outpre[(size_t)(b * N_ + n0 + row) * DIM_ + h * DH_ + dt * 16 + lr] = f2b(v);
            }
        }
    }
}

// A [8192][512] bf16 @ BT [512][512] bf16 (W_out^T) + b_out -> out f32
__global__ __launch_bounds__(256) void gemm_out(
    const u16* __restrict__ A, const u16* __restrict__ BT,
    const float* __restrict__ bout, float* __restrict__ out) {
    __shared__ u16 al[64][72];
    __shared__ u16 bl[64][72];
    const int t = threadIdx.x;
    const int w = t >> 6, l = t & 63, lg = l >> 4, lr = l & 15;
    const int rowbase = blockIdx.y * 64, colbase = blockIdx.x * 64;
    const int r = t >> 2, cg = (t & 3) * 16;

    f32x4 acc[4];
#pragma unroll
    for (int i = 0; i < 4; i++) acc[i] = (f32x4){0.f, 0.f, 0.f, 0.f};

    for (int k0 = 0; k0 < DIM_; k0 += 64) {
        const u16* ap = A + (size_t)(rowbase + r) * DIM_ + k0 + cg;
        *(ushort8*)&al[r][cg] = *(const ushort8*)ap;
        *(ushort8*)&al[r][cg + 8] = *(const ushort8*)(ap + 8);
        const u16* bp = BT + (size_t)(colbase + r) * DIM_ + k0 + cg;
        *(ushort8*)&bl[r][cg] = *(const ushort8*)bp;
        *(ushort8*)&bl[r][cg + 8] = *(const ushort8*)(bp + 8);
        __syncthreads();
#pragma unroll
        for (int kk = 0; kk < 64; kk += 32) {
            short8 af = *(const short8*)&al[16 * w + lr][kk + 8 * lg];
#pragma unroll
            for (int ct = 0; ct < 4; ct++) {
                short8 bf = *(const short8*)&bl[ct * 16 + lr][kk + 8 * lg];
                acc[ct] = mfma16(af, bf, acc[ct]);
            }
        }
        __syncthreads();
    }

#pragma unroll
    for (int ct = 0; ct < 4; ct++) {
#pragma unroll
        for (int j = 0; j < 4; j++) {
            int token = rowbase + 16 * w + 4 * lg + j;
            int cc = colbase + ct * 16 + lr;
            out[(size_t)token * DIM_ + cc] = acc[ct][j] + bout[cc];
        }
    }
}

extern "C" void kernel_launch(void* const* d_in, const int* in_sizes, int n_in,
                              void* d_out, int out_size, void* d_ws, size_t ws_size,
                              hipStream_t stream) {
    const float* x      = (const float*)d_in[0];
    const float* policy = (const float*)d_in[1];
    const float* W_qkv  = (const float*)d_in[2];
    const float* W_out  = (const float*)d_in[3];
    const float* b_out  = (const float*)d_in[4];
    float* out = (float*)d_out;
    float* softout = out + (size_t)B_ * N_ * DIM_;

    // ws: wqkvT 1.5M | woutT .5M | Xb 8M | Qw 8M | Kw 8M | Vt 8M | pre 8M | rip 256K | rpo 256K
    char* ws = (char*)d_ws;
    u16* wqkvT = (u16*)ws;
    u16* woutT = (u16*)(ws + 1572864);
    u16* Xb    = (u16*)(ws + 2097152);
    u16* Qw    = (u16*)(ws + 10485760);
    u16* Kw    = (u16*)(ws + 18874368);
    u16* Vt    = (u16*)(ws + 27262976);
    u16* pre   = (u16*)(ws + 35651584);
    float* rip_g = (float*)(ws + 44040192);
    float* rpo_g = (float*)(ws + 44302336);

    cvt_transpose<<<(1536 * 512 + 255) / 256, 256, 0, stream>>>(W_qkv, wqkvT, 512, 1536);
    cvt_transpose<<<(512 * 512 + 255) / 256, 256, 0, stream>>>(W_out, woutT, 512, 512);
    cvt_bf16<<<(B_ * N_ * DIM_ / 8 + 255) / 256, 256, 0, stream>>>(x, Xb, B_ * N_ * DIM_);
    gemm_qkv<<<dim3(24, 128), 256, 0, stream>>>(Xb, wqkvT, Qw, Kw, Vt);
    attn_sums<<<2048, 256, 0, stream>>>(Qw, Kw, policy, rip_g, rpo_g);
    attn_writer<<<2048, 256, 0, stream>>>(Qw, Kw, rip_g, softout);
    attn_pv<<<2048, 256, 0, stream>>>(Qw, Kw, Vt, policy, rpo_g, pre);
    gemm_out<<<dim3(8, 128), 256, 0, stream>>>(pre, woutT, b_out, out);
}

// Round 8
// 262.135 us; speedup vs baseline: 1.2500x; 1.2500x over previous
//
#include <hip/hip_runtime.h>

#define B_ 8
#define N_ 1024
#define DIM_ 512
#define H_ 8
#define DH_ 64
#define SCALE_ 0.125f
#define EPS_ 1e-6f
#define EPSN_ (1e-6f / 1024.0f)
#define C2_ (0.125f * 1.4426950408889634f)   // SCALE * log2(e)

typedef unsigned short u16;
typedef __attribute__((ext_vector_type(8))) short short8;
typedef __attribute__((ext_vector_type(8))) unsigned short ushort8;
typedef __attribute__((ext_vector_type(4))) unsigned short ushort4v;
typedef __attribute__((ext_vector_type(4))) float f32x4;

__device__ __forceinline__ u16 f2b(float f) {
    union { float f; unsigned u; } v; v.f = f;
    unsigned r = v.u + 0x7fffu + ((v.u >> 16) & 1u);
    return (u16)(r >> 16);
}

__device__ __forceinline__ f32x4 mfma16(short8 a, short8 b, f32x4 c) {
    return __builtin_amdgcn_mfma_f32_16x16x32_bf16(a, b, c, 0, 0, 0);
}

// in [R][C] f32 -> out [C][R] bf16
__global__ void cvt_transpose(const float* __restrict__ in, u16* __restrict__ out,
                              int R, int C) {
    int idx = blockIdx.x * 256 + threadIdx.x;
    if (idx >= R * C) return;
    int c = idx / R, r = idx - c * R;
    out[idx] = f2b(in[(size_t)r * C + c]);
}

// flat f32 -> bf16, 8 elems/thread
__global__ void cvt_bf16(const float* __restrict__ in, u16* __restrict__ out, int n) {
    int idx = (blockIdx.x * 256 + threadIdx.x) * 8;
    if (idx >= n) return;
    float4 f0 = *(const float4*)(in + idx);
    float4 f1 = *(const float4*)(in + idx + 4);
    ushort8 o;
    o[0]=f2b(f0.x); o[1]=f2b(f0.y); o[2]=f2b(f0.z); o[3]=f2b(f0.w);
    o[4]=f2b(f1.x); o[5]=f2b(f1.y); o[6]=f2b(f1.z); o[7]=f2b(f1.w);
    *(ushort8*)(out + idx) = o;
}

// Xb [8192][512] bf16 @ BT [1536][512] bf16 (W_qkv^T) -> scatter Q,K,Vt bf16
__global__ __launch_bounds__(256) void gemm_qkv(
    const u16* __restrict__ Xb, const u16* __restrict__ BT,
    u16* __restrict__ Qw, u16* __restrict__ Kw, u16* __restrict__ Vt) {
    __shared__ u16 al[64][72];
    __shared__ u16 bl[64][72];
    const int t = threadIdx.x;
    const int w = t >> 6, l = t & 63, lg = l >> 4, lr = l & 15;
    const int rowbase = blockIdx.y * 64, colbase = blockIdx.x * 64;
    const int r = t >> 2, cg = (t & 3) * 16;

    f32x4 acc[4];
#pragma unroll
    for (int i = 0; i < 4; i++) acc[i] = (f32x4){0.f, 0.f, 0.f, 0.f};

    for (int k0 = 0; k0 < DIM_; k0 += 64) {
        const u16* ap = Xb + (size_t)(rowbase + r) * DIM_ + k0 + cg;
        *(ushort8*)&al[r][cg] = *(const ushort8*)ap;
        *(ushort8*)&al[r][cg + 8] = *(const ushort8*)(ap + 8);
        const u16* bp = BT + (size_t)(colbase + r) * DIM_ + k0 + cg;
        *(ushort8*)&bl[r][cg] = *(const ushort8*)bp;
        *(ushort8*)&bl[r][cg + 8] = *(const ushort8*)(bp + 8);
        __syncthreads();
#pragma unroll
        for (int kk = 0; kk < 64; kk += 32) {
            short8 af = *(const short8*)&al[16 * w + lr][kk + 8 * lg];
#pragma unroll
            for (int ct = 0; ct < 4; ct++) {
                short8 bf = *(const short8*)&bl[ct * 16 + lr][kk + 8 * lg];
                acc[ct] = mfma16(af, bf, acc[ct]);
            }
        }
        __syncthreads();
    }

#pragma unroll
    for (int ct = 0; ct < 4; ct++) {
#pragma unroll
        for (int j = 0; j < 4; j++) {
            int token = rowbase + 16 * w + 4 * lg + j;
            int b = token >> 10, n = token & (N_ - 1);
            int c = colbase + ct * 16 + lr;
            u16 v = f2b(acc[ct][j]);
            if (c < 512) {
                int h = c >> 6, d = c & 63;
                Qw[((size_t)(b * H_ + h) * N_ + n) * DH_ + d] = v;
            } else if (c < 1024) {
                int c2 = c - 512, h = c2 >> 6, d = c2 & 63;
                Kw[((size_t)(b * H_ + h) * N_ + n) * DH_ + d] = v;
            } else {
                int c2 = c - 1024, h = c2 >> 6, d = c2 & 63;
                Vt[((size_t)(b * H_ + h) * DH_ + d) * N_ + n] = v;
            }
        }
    }
}

// QK tile c (64 cols): compute d, store plain softmax, pack policy P into WL
#define QKTILE(c, WL) do {                                                    \
    _Pragma("unroll")                                                         \
    for (int sub = 0; sub < 4; ++sub) {                                       \
        const int jt = (c) * 4 + sub;                                         \
        const u16* kp = Kb + (size_t)(jt * 16 + lr) * DH_ + 8 * lg;           \
        short8 kf0 = *(const short8*)kp;                                      \
        short8 kf1 = *(const short8*)(kp + 32);                               \
        f32x4 d = {0.f, 0.f, 0.f, 0.f};                                       \
        d = mfma16(kf0, qf0, d);                                              \
        d = mfma16(kf1, qf1, d);                                              \
        const int kb2 = jt * 16 + 4 * lg;                                     \
        f32x4 m4 = *(const f32x4*)&maskL[kb2];                                \
        f32x4 ov; ushort4v wv;                                                \
        _Pragma("unroll")                                                     \
        for (int j = 0; j < 4; ++j) {                                         \
            float E = exp2f(d[j] * C2_);                                      \
            ov[j] = E * rip;                                                  \
            float mm = (kb2 + j == q) ? 1.f : m4[j];                          \
            wv[j] = f2b(fmaf(E * mm, rpo, eb));                               \
        }                                                                     \
        *(f32x4*)(srow + jt * 16 + 4 * lg) = ov;                              \
        *(ushort4v*)&WL[wid][lr][sub * 16 + 4 * lg] = wv;                     \
    }                                                                         \
} while (0)

// PV on tile c using P already in WL (written in the PREVIOUS phase)
#define PVTILE(c, WL) do {                                                    \
    __builtin_amdgcn_s_setprio(1);                                            \
    _Pragma("unroll")                                                         \
    for (int ks = 0; ks < 64; ks += 32) {                                     \
        short8 af = *(const short8*)&WL[wid][lr][ks + 8 * lg];                \
        _Pragma("unroll")                                                     \
        for (int dt = 0; dt < 4; ++dt) {                                      \
            const u16* vp = Vb + (size_t)(dt * 16 + lr) * N_ + (c) * 64 + ks + 8 * lg; \
            short8 vf = *(const short8*)vp;                                   \
            apv[dt] = mfma16(af, vf, apv[dt]);                                \
        }                                                                     \
    }                                                                         \
    __builtin_amdgcn_s_setprio(0);                                            \
} while (0)

// 1024 blocks = 4/CU exactly (no tail). 4 fully independent waves per block,
// each wave: 16 q-rows x full 1024 cols. 2 sweeps. Double-buffered P-LDS
// (wlA/wlB) so QK(c) overlaps PV(c-1); no barriers after the mask build.
__global__ __launch_bounds__(256, 4) void attn_kernel(
    const u16* __restrict__ Qw, const u16* __restrict__ Kw, const u16* __restrict__ Vt,
    const float* __restrict__ policy, u16* __restrict__ outpre, float* __restrict__ softout) {
    __shared__ u16 wlA[4][16][72];
    __shared__ u16 wlB[4][16][72];
    __shared__ float maskL[N_];
    const int t = threadIdx.x;
    const int wid = t >> 6, l = t & 63, lg = l >> 4, lr = l & 15;
    // bid -> (xcd, r); bh = g*8+xcd keeps each (b,h)'s K/V on one XCD L2
    const int bid = blockIdx.x;              // 1024 = 8 xcd * 128
    const int xcd = bid & 7, r = bid >> 3;
    const int g = r >> 4, rt = r & 15;
    const int bh = g * 8 + xcd;
    const int b = bh >> 3, h = bh & 7;
    const int n0 = rt * 64 + wid * 16;
    const int q = n0 + lr;                   // this lane's q-row

    const u16* Qb = Qw + ((size_t)bh * N_ + n0) * DH_;
    const u16* Kb = Kw + (size_t)bh * N_ * DH_;
    const u16* Vb = Vt + (size_t)bh * DH_ * N_;
    const float* pol = policy + b * N_;

    {
        float4 pv = *(const float4*)(pol + t * 4);
        maskL[t * 4 + 0] = pv.x > 0.5f ? 1.f : 0.f;
        maskL[t * 4 + 1] = pv.y > 0.5f ? 1.f : 0.f;
        maskL[t * 4 + 2] = pv.z > 0.5f ? 1.f : 0.f;
        maskL[t * 4 + 3] = pv.w > 0.5f ? 1.f : 0.f;
    }
    __syncthreads();

    short8 qf0 = *(const short8*)(Qb + lr * DH_ + 8 * lg);
    short8 qf1 = *(const short8*)(Qb + lr * DH_ + 32 + 8 * lg);

    // ---- pass 1: row sums (manual K prefetch, no barriers) ----
    float sp = 0.f, so = 0.f;
    {
        const u16* kp0 = Kb + (size_t)lr * DH_ + 8 * lg;
        short8 kc0 = *(const short8*)kp0;
        short8 kc1 = *(const short8*)(kp0 + 32);
#pragma unroll 2
        for (int jt = 0; jt < 64; ++jt) {
            const int jn = (jt + 1 < 64) ? jt + 1 : jt;
            const u16* np = Kb + (size_t)(jn * 16 + lr) * DH_ + 8 * lg;
            short8 nf0 = *(const short8*)np;
            short8 nf1 = *(const short8*)(np + 32);
            f32x4 d = {0.f, 0.f, 0.f, 0.f};
            d = mfma16(kc0, qf0, d);
            d = mfma16(kc1, qf1, d);
            const int kb2 = jt * 16 + 4 * lg;
            f32x4 m4 = *(const f32x4*)&maskL[kb2];
#pragma unroll
            for (int j = 0; j < 4; ++j) {
                float E = exp2f(d[j] * C2_);
                float mm = (kb2 + j == q) ? 1.f : m4[j];
                sp += E;
                so = fmaf(E, mm, so);
            }
            kc0 = nf0; kc1 = nf1;
        }
    }
    // reduce across the 4 lg-groups; every lane ends with its row's totals
    sp += __shfl_xor(sp, 16); sp += __shfl_xor(sp, 32);
    so += __shfl_xor(so, 16); so += __shfl_xor(so, 32);
    const float rip = 1.f / sp;
    const float rpo = 1.f / (so + EPS_);
    const float eb = EPSN_ * rpo;

    // ---- pass 2: softmax stream + PV, software-pipelined through wlA/wlB ----
    f32x4 apv[4];
#pragma unroll
    for (int i = 0; i < 4; i++) apv[i] = (f32x4){0, 0, 0, 0};
    float* srow = softout + ((size_t)bh * N_ + q) * N_;

    QKTILE(0, wlA);
    for (int cc = 0; cc < 7; ++cc) {
        const int c1 = 2 * cc + 1, c2 = 2 * cc + 2;
        QKTILE(c1, wlB);
        PVTILE(2 * cc, wlA);
        QKTILE(c2, wlA);
        PVTILE(c1, wlB);
    }
    QKTILE(15, wlB);
    PVTILE(14, wlA);
    PVTILE(15, wlB);

#pragma unroll
    for (int dt = 0; dt < 4; dt++) {
#pragma unroll
        for (int j = 0; j < 4; j++) {
            outpre[(size_t)(b * N_ + n0 + 4 * lg + j) * DIM_ + h * DH_ + dt * 16 + lr]
                = f2b(apv[dt][j]);
        }
    }
}

// A [8192][512] bf16 @ BT [512][512] bf16 (W_out^T) + b_out -> out f32
__global__ __launch_bounds__(256) void gemm_out(
    const u16* __restrict__ A, const u16* __restrict__ BT,
    const float* __restrict__ bout, float* __restrict__ out) {
    __shared__ u16 al[64][72];
    __shared__ u16 bl[64][72];
    const int t = threadIdx.x;
    const int w = t >> 6, l = t & 63, lg = l >> 4, lr = l & 15;
    const int rowbase = blockIdx.y * 64, colbase = blockIdx.x * 64;
    const int r = t >> 2, cg = (t & 3) * 16;

    f32x4 acc[4];
#pragma unroll
    for (int i = 0; i < 4; i++) acc[i] = (f32x4){0.f, 0.f, 0.f, 0.f};

    for (int k0 = 0; k0 < DIM_; k0 += 64) {
        const u16* ap = A + (size_t)(rowbase + r) * DIM_ + k0 + cg;
        *(ushort8*)&al[r][cg] = *(const ushort8*)ap;
        *(ushort8*)&al[r][cg + 8] = *(const ushort8*)(ap + 8);
        const u16* bp = BT + (size_t)(colbase + r) * DIM_ + k0 + cg;
        *(ushort8*)&bl[r][cg] = *(const ushort8*)bp;
        *(ushort8*)&bl[r][cg + 8] = *(const ushort8*)(bp + 8);
        __syncthreads();
#pragma unroll
        for (int kk = 0; kk < 64; kk += 32) {
            short8 af = *(const short8*)&al[16 * w + lr][kk + 8 * lg];
#pragma unroll
            for (int ct = 0; ct < 4; ct++) {
                short8 bf = *(const short8*)&bl[ct * 16 + lr][kk + 8 * lg];
                acc[ct] = mfma16(af, bf, acc[ct]);
            }
        }
        __syncthreads();
    }

#pragma unroll
    for (int ct = 0; ct < 4; ct++) {
#pragma unroll
        for (int j = 0; j < 4; j++) {
            int token = rowbase + 16 * w + 4 * lg + j;
            int cc = colbase + ct * 16 + lr;
            out[(size_t)token * DIM_ + cc] = acc[ct][j] + bout[cc];
        }
    }
}

extern "C" void kernel_launch(void* const* d_in, const int* in_sizes, int n_in,
                              void* d_out, int out_size, void* d_ws, size_t ws_size,
                              hipStream_t stream) {
    const float* x      = (const float*)d_in[0];
    const float* policy = (const float*)d_in[1];
    const float* W_qkv  = (const float*)d_in[2];
    const float* W_out  = (const float*)d_in[3];
    const float* b_out  = (const float*)d_in[4];
    float* out = (float*)d_out;
    float* softout = out + (size_t)B_ * N_ * DIM_;

    // ws: wqkvT 1.5M | woutT .5M | Xb 8M | Qw 8M | Kw 8M | Vt 8M | pre 8M
    char* ws = (char*)d_ws;
    u16* wqkvT = (u16*)ws;
    u16* woutT = (u16*)(ws + 1572864);
    u16* Xb    = (u16*)(ws + 2097152);
    u16* Qw    = (u16*)(ws + 10485760);
    u16* Kw    = (u16*)(ws + 18874368);
    u16* Vt    = (u16*)(ws + 27262976);
    u16* pre   = (u16*)(ws + 35651584);

    cvt_transpose<<<(1536 * 512 + 255) / 256, 256, 0, stream>>>(W_qkv, wqkvT, 512, 1536);
    cvt_transpose<<<(512 * 512 + 255) / 256, 256, 0, stream>>>(W_out, woutT, 512, 512);
    cvt_bf16<<<(B_ * N_ * DIM_ / 8 + 255) / 256, 256, 0, stream>>>(x, Xb, B_ * N_ * DIM_);
    gemm_qkv<<<dim3(24, 128), 256, 0, stream>>>(Xb, wqkvT, Qw, Kw, Vt);
    attn_kernel<<<1024, 256, 0, stream>>>(Qw, Kw, Vt, policy, pre, softout);
    gemm_out<<<dim3(8, 128), 256, 0, stream>>>(pre, woutT, b_out, out);
}